// Round 5
// baseline (280.879 us; speedup 1.0000x reference)
//
#include <hip/hip_runtime.h>
#include <hip/hip_bf16.h>
#include <math.h>

#define BB   8
#define NN   2048
#define CC   256
#define MTOT (BB * NN)   // 16384

typedef __bf16 bf16_t;
typedef bf16_t    bf16x8 __attribute__((ext_vector_type(8)));
typedef _Float16  halfx8 __attribute__((ext_vector_type(8)));
typedef float     floatx4 __attribute__((ext_vector_type(4)));

#define LOG2E 1.44269504088896f

// async global->LDS, 16 bytes per lane. LDS dest must be wave-uniform base + lane*16.
__device__ __forceinline__ void gl_lds16(const bf16_t* g, bf16_t* l) {
    __builtin_amdgcn_global_load_lds(
        (const __attribute__((address_space(1))) unsigned int*)g,
        (__attribute__((address_space(3))) unsigned int*)l, 16, 0, 0);
}

// ---------------------------------------------------------------------------
// NT bf16 GEMM: C[m][n] = sum_k A[m][k] * B[n][k]  (+bias, relu optional)
// 128x128 tile, K fixed = 256, 256 threads (2x2 waves of 64x64), 16x16x32 MFMA.
// OMODE: 0 = fp32 out, 1 = bf16 out, 2 = fp16 out.
// DO_STATS: emit per-column (max, sumexp) partials over this block's 128 rows.
// ---------------------------------------------------------------------------
template<int OMODE, bool BIASRELU, bool DO_STATS>
__global__ __launch_bounds__(256, 3)
void gemm_nt(const bf16_t* __restrict__ A, const bf16_t* __restrict__ B,
             void* __restrict__ C, const float* __restrict__ bias,
             int lda, int ldb, int ldc,
             long strideA, long strideB, long strideC,
             float* __restrict__ pm, float* __restrict__ pl)
{
    const int b = blockIdx.z;
    A += (long)b * strideA;
    B += (long)b * strideB;
    const int m0 = blockIdx.y * 128;
    const int n0 = blockIdx.x * 128;

    __shared__ bf16_t As[128 * 32];
    __shared__ bf16_t Bs[128 * 32];
    __shared__ float  smx[4][4][16];
    __shared__ float  ssm[4][4][16];

    const int tid  = threadIdx.x;
    const int wid  = tid >> 6, lane = tid & 63;
    const int wm   = (wid >> 1) * 64, wn = (wid & 1) * 64;
    const int fr   = lane & 15;
    const int kb   = (lane >> 4) * 8;

    floatx4 acc[4][4] = {};

    for (int k0 = 0; k0 < 256; k0 += 32) {
#pragma unroll
        for (int r = 0; r < 2; ++r) {
            const int lin = tid + r * 256;
            const int rw  = lin >> 2, kc = lin & 3;
            gl_lds16(A + (long)(m0 + rw) * lda + k0 + kc * 8, As + lin * 8);
            gl_lds16(B + (long)(n0 + rw) * ldb + k0 + kc * 8, Bs + lin * 8);
        }
        __syncthreads();
        bf16x8 af[4], bf[4];
#pragma unroll
        for (int f = 0; f < 4; ++f) {
            af[f] = *(const bf16x8*)(As + (wm + f * 16 + fr) * 32 + kb);
            bf[f] = *(const bf16x8*)(Bs + (wn + f * 16 + fr) * 32 + kb);
        }
#pragma unroll
        for (int f = 0; f < 4; ++f)
#pragma unroll
            for (int g = 0; g < 4; ++g)
                acc[f][g] = __builtin_amdgcn_mfma_f32_16x16x32_bf16(af[f], bf[g], acc[f][g], 0, 0, 0);
        __syncthreads();
    }

    // C/D layout: col = lane&15, row = (lane>>4)*4 + reg
    const int rbase = (lane >> 4) * 4;
#pragma unroll
    for (int g = 0; g < 4; ++g) {
        const int n = n0 + wn + g * 16 + fr;
        const float bv = BIASRELU ? bias[n] : 0.0f;
#pragma unroll
        for (int f = 0; f < 4; ++f) {
#pragma unroll
            for (int r = 0; r < 4; ++r) {
                const int m = m0 + wm + f * 16 + rbase + r;
                float v = acc[f][g][r] + bv;
                if (BIASRELU) v = v > 0.0f ? v : 0.0f;
                if (OMODE == 0)
                    ((float*)C)[(long)b * strideC + (long)m * ldc + n] = v;
                else if (OMODE == 1)
                    ((bf16_t*)C)[(long)b * strideC + (long)m * ldc + n] = (bf16_t)v;
                else
                    ((_Float16*)C)[(long)b * strideC + (long)m * ldc + n] = (_Float16)v;
            }
        }
    }

    if (DO_STATS) {
        float lmax[4], lsum[4];
#pragma unroll
        for (int g = 0; g < 4; ++g) {
            float m = -1e30f;
#pragma unroll
            for (int f = 0; f < 4; ++f)
#pragma unroll
                for (int r = 0; r < 4; ++r) m = fmaxf(m, acc[f][g][r]);
            m = fmaxf(m, __shfl_xor(m, 16));
            m = fmaxf(m, __shfl_xor(m, 32));
            float s = 0.0f;
#pragma unroll
            for (int f = 0; f < 4; ++f)
#pragma unroll
                for (int r = 0; r < 4; ++r) s += __expf(acc[f][g][r] - m);
            s += __shfl_xor(s, 16);
            s += __shfl_xor(s, 32);
            lmax[g] = m; lsum[g] = s;
        }
        if (lane < 16) {
#pragma unroll
            for (int g = 0; g < 4; ++g) {
                smx[wid][g][lane] = lmax[g];
                ssm[wid][g][lane] = lsum[g];
            }
        }
        __syncthreads();
        if (tid < 128) {
            const int pair = tid >> 6;
            const int idx  = tid & 63;
            const int g = idx >> 4, f2 = idx & 15;
            const float m0v = smx[pair][g][f2], m1v = smx[pair + 2][g][f2];
            const float M = fmaxf(m0v, m1v);
            const float L = ssm[pair][g][f2] * __expf(m0v - M) +
                            ssm[pair + 2][g][f2] * __expf(m1v - M);
            const int n = n0 + pair * 64 + g * 16 + f2;
            const long o = ((long)b * 16 + blockIdx.y) * NN + n;
            pm[o] = M;
            pl[o] = L;
        }
    }
}

// ---------------------------------------------------------------------------
// Merge 16 per-m-tile partials per column into c2[n] = (mx + ln L) * log2(e).
// Then P~[m,n] = exp2(St[m,n]*log2e - c2[n]).
// ---------------------------------------------------------------------------
__global__ __launch_bounds__(256)
void stats_combine(const float* __restrict__ pm, const float* __restrict__ pl,
                   float* __restrict__ c2)
{
    const int i = blockIdx.x * 256 + threadIdx.x;
    const int b = i >> 11, n = i & 2047;
    float M = -1e30f, L = 0.0f;
#pragma unroll
    for (int t = 0; t < 16; ++t) {
        const long o = ((long)b * 16 + t) * NN + n;
        const float m = pm[o], l = pl[o];
        const float nm = fmaxf(M, m);
        L = L * __expf(M - nm) + l * __expf(m - nm);
        M = nm;
    }
    c2[i] = (M + logf(L)) * LOG2E;
}

// ---------------------------------------------------------------------------
// out[m][u] = relu( sum_n exp2(St[m][n]*log2e - c2[n]) * qmT[u][n] + bm[u] )
// Barrier-free, LDS-free: each lane loads its MFMA fragments directly from
// global (A-frag = halfx8 of its own St row, exp'd in-register; B-frags from
// qmT which is L1/L2-resident). Wave tile 16m x 128u; block 64m x 128u.
// Grid (32, 2, BB) = 512 blocks.
// ---------------------------------------------------------------------------
__global__ __launch_bounds__(256, 2)
void att_out(const _Float16* __restrict__ St, const bf16_t* __restrict__ qmT,
             const float* __restrict__ c2, const float* __restrict__ bm,
             float* __restrict__ out)
{
    const int b  = blockIdx.z;
    const int m0 = blockIdx.x * 64;
    const int u0 = blockIdx.y * 128;
    const _Float16* S  = St  + (long)b * NN * NN;
    const bf16_t*   Q  = qmT + (long)b * 256 * NN;
    const float*    C2 = c2  + b * NN;
    float*          O  = out + (long)b * NN * 256;

    const int tid  = threadIdx.x;
    const int wid  = tid >> 6, lane = tid & 63;
    const int fr   = lane & 15;
    const int kb   = (lane >> 4) * 8;

    const _Float16* Srow = S + (long)(m0 + wid * 16 + fr) * NN + kb;
    const bf16_t*   Qrow = Q + (long)(u0 + fr) * NN + kb;

    floatx4 acc[8] = {};

#pragma unroll 2
    for (int n0 = 0; n0 < NN; n0 += 32) {
        const halfx8 hv = *(const halfx8*)(Srow + n0);
        const float4 ca = *(const float4*)(C2 + n0 + kb);
        const float4 cb = *(const float4*)(C2 + n0 + kb + 4);
        bf16x8 p;
        p[0] = (bf16_t)exp2f(fmaf((float)hv[0], LOG2E, -ca.x));
        p[1] = (bf16_t)exp2f(fmaf((float)hv[1], LOG2E, -ca.y));
        p[2] = (bf16_t)exp2f(fmaf((float)hv[2], LOG2E, -ca.z));
        p[3] = (bf16_t)exp2f(fmaf((float)hv[3], LOG2E, -ca.w));
        p[4] = (bf16_t)exp2f(fmaf((float)hv[4], LOG2E, -cb.x));
        p[5] = (bf16_t)exp2f(fmaf((float)hv[5], LOG2E, -cb.y));
        p[6] = (bf16_t)exp2f(fmaf((float)hv[6], LOG2E, -cb.z));
        p[7] = (bf16_t)exp2f(fmaf((float)hv[7], LOG2E, -cb.w));

        bf16x8 bv[8];
#pragma unroll
        for (int g = 0; g < 8; ++g)
            bv[g] = *(const bf16x8*)(Qrow + (long)g * 16 * NN + n0);
#pragma unroll
        for (int g = 0; g < 8; ++g)
            acc[g] = __builtin_amdgcn_mfma_f32_16x16x32_bf16(p, bv[g], acc[g], 0, 0, 0);
    }

    // D layout: col(=u frag) = lane&15, row(=m frag) = (lane>>4)*4 + reg
    const int rbase = (lane >> 4) * 4;
#pragma unroll
    for (int g = 0; g < 8; ++g) {
        const int u = u0 + g * 16 + fr;
        const float bvv = bm[u];
#pragma unroll
        for (int r = 0; r < 4; ++r) {
            const int m = m0 + wid * 16 + rbase + r;
            const float v = acc[g][r] + bvv;
            O[(long)m * 256 + u] = v > 0.0f ? v : 0.0f;
        }
    }
}

// ---------------------------------------------------------------------------
// Helpers
// ---------------------------------------------------------------------------
__global__ __launch_bounds__(256)
void cvt_bf16(const float* __restrict__ x, bf16_t* __restrict__ y)
{
    const long i = ((long)blockIdx.x * 256 + threadIdx.x) * 8;
    const float4 a = *(const float4*)(x + i);
    const float4 b = *(const float4*)(x + i + 4);
    bf16x8 o;
    o[0] = (bf16_t)a.x; o[1] = (bf16_t)a.y; o[2] = (bf16_t)a.z; o[3] = (bf16_t)a.w;
    o[4] = (bf16_t)b.x; o[5] = (bf16_t)b.y; o[6] = (bf16_t)b.z; o[7] = (bf16_t)b.w;
    *(bf16x8*)(y + i) = o;
}

// z=0: Wq -> WqkT[0:256), z=1: Wk -> WqkT[256:512), z=2: Wm -> WmT.
// Block (0,0,0) also concatenates [bq|bk] into bqk.
__global__ __launch_bounds__(256)
void prep_w(const float* __restrict__ Wq, const float* __restrict__ Wk,
            const float* __restrict__ Wm, const float* __restrict__ bq,
            const float* __restrict__ bk, bf16_t* __restrict__ WqkT,
            bf16_t* __restrict__ WmT, float* __restrict__ bqk)
{
    const int z = blockIdx.z;
    const float* W = (z == 0) ? Wq : (z == 1) ? Wk : Wm;
    bf16_t* Wt = (z == 0) ? WqkT : (z == 1) ? (WqkT + 256 * 256) : WmT;
    __shared__ float t[32][33];
    const int n0 = blockIdx.x * 32, k0 = blockIdx.y * 32;
    const int tx = threadIdx.x & 31, ty = threadIdx.x >> 5;
    for (int i = ty; i < 32; i += 8) t[i][tx] = W[(k0 + i) * 256 + n0 + tx];
    __syncthreads();
    for (int i = ty; i < 32; i += 8) Wt[(n0 + i) * 256 + k0 + tx] = (bf16_t)t[tx][i];
    if (z == 0 && blockIdx.x == 0 && blockIdx.y == 0) {
        bqk[threadIdx.x]       = bq[threadIdx.x];
        bqk[256 + threadIdx.x] = bk[threadIdx.x];
    }
}

extern "C" void kernel_launch(void* const* d_in, const int* in_sizes, int n_in,
                              void* d_out, int out_size, void* d_ws, size_t ws_size,
                              hipStream_t stream)
{
    (void)in_sizes; (void)n_in; (void)out_size; (void)ws_size;
    const float* x  = (const float*)d_in[0];
    const float* Wq = (const float*)d_in[1];
    const float* bq = (const float*)d_in[2];
    const float* Wk = (const float*)d_in[3];
    const float* bk = (const float*)d_in[4];
    const float* Wm = (const float*)d_in[5];
    const float* bm = (const float*)d_in[6];
    float* out = (float*)d_out;

    // Workspace: St fp16 67.1 MB | x_bf 8.4 | qk 16.8 | qmT 8.4 |
    // WqkT 0.26 | WmT 0.13 | bqk | pm/pl 2x1 MB | c2 64 KB  (~103 MB)
    char* w = (char*)d_ws;
    _Float16* St   = (_Float16*)w;                  w += (size_t)BB * NN * NN * 2;
    bf16_t* x_bf   = (bf16_t*)w;                    w += (size_t)MTOT * 256 * 2;
    bf16_t* qk     = (bf16_t*)w;                    w += (size_t)MTOT * 512 * 2;
    bf16_t* qmT    = (bf16_t*)w;                    w += (size_t)MTOT * 256 * 2;
    bf16_t* WqkT   = (bf16_t*)w;                    w += 512 * 256 * 2;
    bf16_t* WmT    = (bf16_t*)w;                    w += 256 * 256 * 2;
    float*  bqk    = (float*)w;                     w += 512 * 4;
    float*  pm     = (float*)w;                     w += (size_t)BB * 16 * NN * 4;
    float*  pl     = (float*)w;                     w += (size_t)BB * 16 * NN * 4;
    float*  c2b    = (float*)w;

    cvt_bf16<<<dim3(MTOT * 256 / (256 * 8)), 256, 0, stream>>>(x, x_bf);
    prep_w<<<dim3(8, 8, 3), 256, 0, stream>>>(Wq, Wk, Wm, bq, bk, WqkT, WmT, bqk);

    // [q | k] = relu(x @ [Wq|Wk] + [bq|bk])  (bf16, ldc=512)
    gemm_nt<1, true, false><<<dim3(4, 128, 1), 256, 0, stream>>>(
        x_bf, WqkT, qk, bqk, 256, 256, 512, 0, 0, 0, nullptr, nullptr);

    // qmT[u][m] = sum_k WmT[u][k] * q[m][k]  (= (q @ Wm)^T, bf16, ldc=NN)
    gemm_nt<1, false, false><<<dim3(16, 2, BB), 256, 0, stream>>>(
        WmT, qk, qmT, nullptr, 256, 512, NN,
        0, (long)NN * 512, (long)256 * NN, nullptr, nullptr);

    // St[m][n] = q[m]·k[n]  (fp16 out) + fused per-column softmax stats
    gemm_nt<2, false, true><<<dim3(16, 16, BB), 256, 0, stream>>>(
        qk, qk + 256, St, nullptr, 512, 512, NN,
        (long)NN * 512, (long)NN * 512, (long)NN * NN, pm, pl);

    stats_combine<<<dim3(MTOT / 256), 256, 0, stream>>>(pm, pl, c2b);

    // out = relu(P~ @ qm + bm)   (P never materialized)
    att_out<<<dim3(32, 2, BB), 256, 0, stream>>>(St, qmT, c2b, bm, out);
}

// Round 6
// 190.083 us; speedup vs baseline: 1.4777x; 1.4777x over previous
//
#include <hip/hip_runtime.h>
#include <hip/hip_bf16.h>
#include <math.h>

#define BB   8
#define NN   2048
#define CC   256
#define MTOT (BB * NN)   // 16384

typedef __bf16 bf16_t;
typedef bf16_t    bf16x8 __attribute__((ext_vector_type(8)));
typedef _Float16  halfx8 __attribute__((ext_vector_type(8)));
typedef float     floatx4 __attribute__((ext_vector_type(4)));

#define LOG2E 1.44269504088896f

// async global->LDS, 16 bytes per lane. LDS dest must be wave-uniform base + lane*16.
__device__ __forceinline__ void gl_lds16(const bf16_t* g, bf16_t* l) {
    __builtin_amdgcn_global_load_lds(
        (const __attribute__((address_space(1))) unsigned int*)g,
        (__attribute__((address_space(3))) unsigned int*)l, 16, 0, 0);
}

// ---------------------------------------------------------------------------
// NT bf16 GEMM: C[m][n] = sum_k A[m][k] * B[n][k]  (+bias, relu optional)
// 128x128 tile, K fixed = 256, 256 threads (2x2 waves of 64x64), 16x16x32 MFMA.
// OMODE: 0 = fp32 out, 1 = bf16 out, 2 = fp16 out.
// DO_STATS: emit per-column (max, sumexp) partials over this block's 128 rows.
// ---------------------------------------------------------------------------
template<int OMODE, bool BIASRELU, bool DO_STATS>
__global__ __launch_bounds__(256, 3)
void gemm_nt(const bf16_t* __restrict__ A, const bf16_t* __restrict__ B,
             void* __restrict__ C, const float* __restrict__ bias,
             int lda, int ldb, int ldc,
             long strideA, long strideB, long strideC,
             float* __restrict__ pm, float* __restrict__ pl)
{
    const int b = blockIdx.z;
    A += (long)b * strideA;
    B += (long)b * strideB;
    const int m0 = blockIdx.y * 128;
    const int n0 = blockIdx.x * 128;

    __shared__ bf16_t As[128 * 32];
    __shared__ bf16_t Bs[128 * 32];
    __shared__ float  smx[4][4][16];
    __shared__ float  ssm[4][4][16];

    const int tid  = threadIdx.x;
    const int wid  = tid >> 6, lane = tid & 63;
    const int wm   = (wid >> 1) * 64, wn = (wid & 1) * 64;
    const int fr   = lane & 15;
    const int kb   = (lane >> 4) * 8;

    floatx4 acc[4][4] = {};

    for (int k0 = 0; k0 < 256; k0 += 32) {
#pragma unroll
        for (int r = 0; r < 2; ++r) {
            const int lin = tid + r * 256;
            const int rw  = lin >> 2, kc = lin & 3;
            gl_lds16(A + (long)(m0 + rw) * lda + k0 + kc * 8, As + lin * 8);
            gl_lds16(B + (long)(n0 + rw) * ldb + k0 + kc * 8, Bs + lin * 8);
        }
        __syncthreads();
        bf16x8 af[4], bf[4];
#pragma unroll
        for (int f = 0; f < 4; ++f) {
            af[f] = *(const bf16x8*)(As + (wm + f * 16 + fr) * 32 + kb);
            bf[f] = *(const bf16x8*)(Bs + (wn + f * 16 + fr) * 32 + kb);
        }
#pragma unroll
        for (int f = 0; f < 4; ++f)
#pragma unroll
            for (int g = 0; g < 4; ++g)
                acc[f][g] = __builtin_amdgcn_mfma_f32_16x16x32_bf16(af[f], bf[g], acc[f][g], 0, 0, 0);
        __syncthreads();
    }

    // C/D layout: col = lane&15, row = (lane>>4)*4 + reg
    const int rbase = (lane >> 4) * 4;
#pragma unroll
    for (int g = 0; g < 4; ++g) {
        const int n = n0 + wn + g * 16 + fr;
        const float bv = BIASRELU ? bias[n] : 0.0f;
#pragma unroll
        for (int f = 0; f < 4; ++f) {
#pragma unroll
            for (int r = 0; r < 4; ++r) {
                const int m = m0 + wm + f * 16 + rbase + r;
                float v = acc[f][g][r] + bv;
                if (BIASRELU) v = v > 0.0f ? v : 0.0f;
                if (OMODE == 0)
                    ((float*)C)[(long)b * strideC + (long)m * ldc + n] = v;
                else if (OMODE == 1)
                    ((bf16_t*)C)[(long)b * strideC + (long)m * ldc + n] = (bf16_t)v;
                else
                    ((_Float16*)C)[(long)b * strideC + (long)m * ldc + n] = (_Float16)v;
            }
        }
    }

    if (DO_STATS) {
        float lmax[4], lsum[4];
#pragma unroll
        for (int g = 0; g < 4; ++g) {
            float m = -1e30f;
#pragma unroll
            for (int f = 0; f < 4; ++f)
#pragma unroll
                for (int r = 0; r < 4; ++r) m = fmaxf(m, acc[f][g][r]);
            m = fmaxf(m, __shfl_xor(m, 16));
            m = fmaxf(m, __shfl_xor(m, 32));
            float s = 0.0f;
#pragma unroll
            for (int f = 0; f < 4; ++f)
#pragma unroll
                for (int r = 0; r < 4; ++r) s += __expf(acc[f][g][r] - m);
            s += __shfl_xor(s, 16);
            s += __shfl_xor(s, 32);
            lmax[g] = m; lsum[g] = s;
        }
        if (lane < 16) {
#pragma unroll
            for (int g = 0; g < 4; ++g) {
                smx[wid][g][lane] = lmax[g];
                ssm[wid][g][lane] = lsum[g];
            }
        }
        __syncthreads();
        if (tid < 128) {
            const int pair = tid >> 6;
            const int idx  = tid & 63;
            const int g = idx >> 4, f2 = idx & 15;
            const float m0v = smx[pair][g][f2], m1v = smx[pair + 2][g][f2];
            const float M = fmaxf(m0v, m1v);
            const float L = ssm[pair][g][f2] * __expf(m0v - M) +
                            ssm[pair + 2][g][f2] * __expf(m1v - M);
            const int n = n0 + pair * 64 + g * 16 + f2;
            const long o = ((long)b * 16 + blockIdx.y) * NN + n;
            pm[o] = M;
            pl[o] = L;
        }
    }
}

// ---------------------------------------------------------------------------
// Merge 16 per-m-tile partials per column into c2[n] = (mx + ln L) * log2(e).
// Then P~[m,n] = exp2(St[m,n]*log2e - c2[n]).
// ---------------------------------------------------------------------------
__global__ __launch_bounds__(256)
void stats_combine(const float* __restrict__ pm, const float* __restrict__ pl,
                   float* __restrict__ c2)
{
    const int i = blockIdx.x * 256 + threadIdx.x;
    const int b = i >> 11, n = i & 2047;
    float M = -1e30f, L = 0.0f;
#pragma unroll
    for (int t = 0; t < 16; ++t) {
        const long o = ((long)b * 16 + t) * NN + n;
        const float m = pm[o], l = pl[o];
        const float nm = fmaxf(M, m);
        L = L * __expf(M - nm) + l * __expf(m - nm);
        M = nm;
    }
    c2[i] = (M + logf(L)) * LOG2E;
}

// ---------------------------------------------------------------------------
// out[m][u] = relu( sum_n exp2(St[m][n]*log2e - c2[n]) * qmT[u][n] + bm[u] )
// LDS-staged, occupancy-tuned: 32m x 128u block tile, K(n)-step 64,
// grid (64, 2, BB) = 1024 blocks, 4 blocks/CU (16 waves/CU).
// A-tile: St 32x64 fp16 -> exp'd bf16 in LDS (one halfx8 + 8 exp2 per thread).
// B-tile: qmT 128x64 via global_load_lds x4. 8 MFMA/wave per barrier pair.
// ---------------------------------------------------------------------------
__global__ __launch_bounds__(256, 4)
void att_out(const _Float16* __restrict__ St, const bf16_t* __restrict__ qmT,
             const float* __restrict__ c2, const float* __restrict__ bm,
             float* __restrict__ out)
{
    const int b  = blockIdx.z;
    const int m0 = blockIdx.x * 32;
    const int u0 = blockIdx.y * 128;
    const _Float16* S  = St  + (long)b * NN * NN;
    const bf16_t*   Q  = qmT + (long)b * 256 * NN;
    const float*    C2 = c2  + b * NN;
    float*          O  = out + (long)b * NN * 256;

    __shared__ bf16_t As[32 * 64];    // 4 KB  P-tile (exp'd, bf16)
    __shared__ bf16_t Bs[128 * 64];   // 16 KB qmT tile

    const int tid  = threadIdx.x;
    const int wid  = tid >> 6, lane = tid & 63;
    const int wm2  = (wid >> 1) * 16;      // m-half per wave (0 or 16)
    const int wu   = (wid & 1) * 64;       // u-half per wave (0 or 64)
    const int fr   = lane & 15;
    const int kb   = (lane >> 4) * 8;
    const int arow = tid >> 3;             // 0..31  (A staging row)
    const int aseg = tid & 7;              // 8 halves each

    const _Float16* Srow = S + (long)(m0 + arow) * NN + aseg * 8;

    floatx4 acc[4] = {};   // [g: u frags]

    for (int n0 = 0; n0 < NN; n0 += 64) {
        // B: qmT 128 rows x 64 cols bf16 = 8 KB, 4 rounds of 256x16B
#pragma unroll
        for (int r = 0; r < 4; ++r) {
            const int lin = tid + r * 256;
            const int rw  = lin >> 3, kc = lin & 7;
            gl_lds16(Q + (long)(u0 + rw) * NN + n0 + kc * 8, Bs + lin * 8);
        }
        // A: St 32x64 fp16, exp2(s*log2e - c2), pack bf16 -> LDS
        const halfx8 hv = *(const halfx8*)(Srow + n0);
        const float4 ca = *(const float4*)(C2 + n0 + aseg * 8);
        const float4 cb = *(const float4*)(C2 + n0 + aseg * 8 + 4);
        bf16x8 p;
        p[0] = (bf16_t)exp2f(fmaf((float)hv[0], LOG2E, -ca.x));
        p[1] = (bf16_t)exp2f(fmaf((float)hv[1], LOG2E, -ca.y));
        p[2] = (bf16_t)exp2f(fmaf((float)hv[2], LOG2E, -ca.z));
        p[3] = (bf16_t)exp2f(fmaf((float)hv[3], LOG2E, -ca.w));
        p[4] = (bf16_t)exp2f(fmaf((float)hv[4], LOG2E, -cb.x));
        p[5] = (bf16_t)exp2f(fmaf((float)hv[5], LOG2E, -cb.y));
        p[6] = (bf16_t)exp2f(fmaf((float)hv[6], LOG2E, -cb.z));
        p[7] = (bf16_t)exp2f(fmaf((float)hv[7], LOG2E, -cb.w));
        *(bf16x8*)(As + arow * 64 + aseg * 8) = p;
        __syncthreads();

        bf16x8 af[2], bg[4][2];
#pragma unroll
        for (int j = 0; j < 2; ++j)
            af[j] = *(const bf16x8*)(As + (wm2 + fr) * 64 + j * 32 + kb);
#pragma unroll
        for (int g = 0; g < 4; ++g)
#pragma unroll
            for (int j = 0; j < 2; ++j)
                bg[g][j] = *(const bf16x8*)(Bs + (wu + g * 16 + fr) * 64 + j * 32 + kb);
#pragma unroll
        for (int j = 0; j < 2; ++j)
#pragma unroll
            for (int g = 0; g < 4; ++g)
                acc[g] = __builtin_amdgcn_mfma_f32_16x16x32_bf16(af[j], bg[g][j], acc[g], 0, 0, 0);
        __syncthreads();
    }

    // D layout: col(u) = lane&15, row(m) = (lane>>4)*4 + reg
    const int rbase = (lane >> 4) * 4;
#pragma unroll
    for (int g = 0; g < 4; ++g) {
        const int u = u0 + wu + g * 16 + fr;
        const float bvv = bm[u];
#pragma unroll
        for (int r = 0; r < 4; ++r) {
            const int m = m0 + wm2 + rbase + r;
            const float v = acc[g][r] + bvv;
            O[(long)m * 256 + u] = v > 0.0f ? v : 0.0f;
        }
    }
}

// ---------------------------------------------------------------------------
// Helpers
// ---------------------------------------------------------------------------
__global__ __launch_bounds__(256)
void cvt_bf16(const float* __restrict__ x, bf16_t* __restrict__ y)
{
    const long i = ((long)blockIdx.x * 256 + threadIdx.x) * 8;
    const float4 a = *(const float4*)(x + i);
    const float4 b = *(const float4*)(x + i + 4);
    bf16x8 o;
    o[0] = (bf16_t)a.x; o[1] = (bf16_t)a.y; o[2] = (bf16_t)a.z; o[3] = (bf16_t)a.w;
    o[4] = (bf16_t)b.x; o[5] = (bf16_t)b.y; o[6] = (bf16_t)b.z; o[7] = (bf16_t)b.w;
    *(bf16x8*)(y + i) = o;
}

// z=0: Wq -> WqkT[0:256), z=1: Wk -> WqkT[256:512), z=2: Wm -> WmT.
// Block (0,0,0) also concatenates [bq|bk] into bqk.
__global__ __launch_bounds__(256)
void prep_w(const float* __restrict__ Wq, const float* __restrict__ Wk,
            const float* __restrict__ Wm, const float* __restrict__ bq,
            const float* __restrict__ bk, bf16_t* __restrict__ WqkT,
            bf16_t* __restrict__ WmT, float* __restrict__ bqk)
{
    const int z = blockIdx.z;
    const float* W = (z == 0) ? Wq : (z == 1) ? Wk : Wm;
    bf16_t* Wt = (z == 0) ? WqkT : (z == 1) ? (WqkT + 256 * 256) : WmT;
    __shared__ float t[32][33];
    const int n0 = blockIdx.x * 32, k0 = blockIdx.y * 32;
    const int tx = threadIdx.x & 31, ty = threadIdx.x >> 5;
    for (int i = ty; i < 32; i += 8) t[i][tx] = W[(k0 + i) * 256 + n0 + tx];
    __syncthreads();
    for (int i = ty; i < 32; i += 8) Wt[(n0 + i) * 256 + k0 + tx] = (bf16_t)t[tx][i];
    if (z == 0 && blockIdx.x == 0 && blockIdx.y == 0) {
        bqk[threadIdx.x]       = bq[threadIdx.x];
        bqk[256 + threadIdx.x] = bk[threadIdx.x];
    }
}

extern "C" void kernel_launch(void* const* d_in, const int* in_sizes, int n_in,
                              void* d_out, int out_size, void* d_ws, size_t ws_size,
                              hipStream_t stream)
{
    (void)in_sizes; (void)n_in; (void)out_size; (void)ws_size;
    const float* x  = (const float*)d_in[0];
    const float* Wq = (const float*)d_in[1];
    const float* bq = (const float*)d_in[2];
    const float* Wk = (const float*)d_in[3];
    const float* bk = (const float*)d_in[4];
    const float* Wm = (const float*)d_in[5];
    const float* bm = (const float*)d_in[6];
    float* out = (float*)d_out;

    // Workspace: St fp16 67.1 MB | x_bf 8.4 | qk 16.8 | qmT 8.4 |
    // WqkT 0.26 | WmT 0.13 | bqk | pm/pl 2x1 MB | c2 64 KB  (~103 MB)
    char* w = (char*)d_ws;
    _Float16* St   = (_Float16*)w;                  w += (size_t)BB * NN * NN * 2;
    bf16_t* x_bf   = (bf16_t*)w;                    w += (size_t)MTOT * 256 * 2;
    bf16_t* qk     = (bf16_t*)w;                    w += (size_t)MTOT * 512 * 2;
    bf16_t* qmT    = (bf16_t*)w;                    w += (size_t)MTOT * 256 * 2;
    bf16_t* WqkT   = (bf16_t*)w;                    w += 512 * 256 * 2;
    bf16_t* WmT    = (bf16_t*)w;                    w += 256 * 256 * 2;
    float*  bqk    = (float*)w;                     w += 512 * 4;
    float*  pm     = (float*)w;                     w += (size_t)BB * 16 * NN * 4;
    float*  pl     = (float*)w;                     w += (size_t)BB * 16 * NN * 4;
    float*  c2b    = (float*)w;

    cvt_bf16<<<dim3(MTOT * 256 / (256 * 8)), 256, 0, stream>>>(x, x_bf);
    prep_w<<<dim3(8, 8, 3), 256, 0, stream>>>(Wq, Wk, Wm, bq, bk, WqkT, WmT, bqk);

    // [q | k] = relu(x @ [Wq|Wk] + [bq|bk])  (bf16, ldc=512)
    gemm_nt<1, true, false><<<dim3(4, 128, 1), 256, 0, stream>>>(
        x_bf, WqkT, qk, bqk, 256, 256, 512, 0, 0, 0, nullptr, nullptr);

    // qmT[u][m] = sum_k WmT[u][k] * q[m][k]  (= (q @ Wm)^T, bf16, ldc=NN)
    gemm_nt<1, false, false><<<dim3(16, 2, BB), 256, 0, stream>>>(
        WmT, qk, qmT, nullptr, 256, 512, NN,
        0, (long)NN * 512, (long)256 * NN, nullptr, nullptr);

    // St[m][n] = q[m]·k[n]  (fp16 out) + fused per-column softmax stats
    gemm_nt<2, false, true><<<dim3(16, 16, BB), 256, 0, stream>>>(
        qk, qk + 256, St, nullptr, 512, 512, NN,
        (long)NN * 512, (long)NN * 512, (long)NN * NN, pm, pl);

    stats_combine<<<dim3(MTOT / 256), 256, 0, stream>>>(pm, pl, c2b);

    // out = relu(P~ @ qm + bm)   (P never materialized)
    att_out<<<dim3(64, 2, BB), 256, 0, stream>>>(St, qmT, c2b, bm, out);
}

// Round 7
// 179.085 us; speedup vs baseline: 1.5684x; 1.0614x over previous
//
#include <hip/hip_runtime.h>
#include <hip/hip_bf16.h>
#include <math.h>

#define BB   8
#define NN   2048
#define CC   256
#define MTOT (BB * NN)   // 16384

typedef __bf16 bf16_t;
typedef bf16_t    bf16x8 __attribute__((ext_vector_type(8)));
typedef _Float16  halfx8 __attribute__((ext_vector_type(8)));
typedef float     floatx4 __attribute__((ext_vector_type(4)));

#define LOG2E 1.44269504088896f

// async global->LDS, 16 bytes per lane. LDS dest must be wave-uniform base + lane*16.
__device__ __forceinline__ void gl_lds16(const bf16_t* g, bf16_t* l) {
    __builtin_amdgcn_global_load_lds(
        (const __attribute__((address_space(1))) unsigned int*)g,
        (__attribute__((address_space(3))) unsigned int*)l, 16, 0, 0);
}

// ---------------------------------------------------------------------------
// NT bf16 GEMM: C[m][n] = sum_k A[m][k] * B[n][k]  (+bias, relu optional)
// 128x128 tile, K fixed = 256, 256 threads (2x2 waves of 64x64), 16x16x32 MFMA.
// OMODE: 0 = fp32 out, 1 = bf16 out, 2 = fp16 out.
// DO_STATS: emit per-column (max, sumexp) partials over this block's 128 rows.
// ---------------------------------------------------------------------------
template<int OMODE, bool BIASRELU, bool DO_STATS>
__global__ __launch_bounds__(256, 3)
void gemm_nt(const bf16_t* __restrict__ A, const bf16_t* __restrict__ B,
             void* __restrict__ C, const float* __restrict__ bias,
             int lda, int ldb, int ldc,
             long strideA, long strideB, long strideC,
             float* __restrict__ pm, float* __restrict__ pl)
{
    const int b = blockIdx.z;
    A += (long)b * strideA;
    B += (long)b * strideB;
    const int m0 = blockIdx.y * 128;
    const int n0 = blockIdx.x * 128;

    __shared__ bf16_t As[128 * 32];
    __shared__ bf16_t Bs[128 * 32];
    __shared__ float  smx[4][4][16];
    __shared__ float  ssm[4][4][16];

    const int tid  = threadIdx.x;
    const int wid  = tid >> 6, lane = tid & 63;
    const int wm   = (wid >> 1) * 64, wn = (wid & 1) * 64;
    const int fr   = lane & 15;
    const int kb   = (lane >> 4) * 8;

    floatx4 acc[4][4] = {};

    for (int k0 = 0; k0 < 256; k0 += 32) {
#pragma unroll
        for (int r = 0; r < 2; ++r) {
            const int lin = tid + r * 256;
            const int rw  = lin >> 2, kc = lin & 3;
            gl_lds16(A + (long)(m0 + rw) * lda + k0 + kc * 8, As + lin * 8);
            gl_lds16(B + (long)(n0 + rw) * ldb + k0 + kc * 8, Bs + lin * 8);
        }
        __syncthreads();
        bf16x8 af[4], bf[4];
#pragma unroll
        for (int f = 0; f < 4; ++f) {
            af[f] = *(const bf16x8*)(As + (wm + f * 16 + fr) * 32 + kb);
            bf[f] = *(const bf16x8*)(Bs + (wn + f * 16 + fr) * 32 + kb);
        }
#pragma unroll
        for (int f = 0; f < 4; ++f)
#pragma unroll
            for (int g = 0; g < 4; ++g)
                acc[f][g] = __builtin_amdgcn_mfma_f32_16x16x32_bf16(af[f], bf[g], acc[f][g], 0, 0, 0);
        __syncthreads();
    }

    // C/D layout: col = lane&15, row = (lane>>4)*4 + reg
    const int rbase = (lane >> 4) * 4;
#pragma unroll
    for (int g = 0; g < 4; ++g) {
        const int n = n0 + wn + g * 16 + fr;
        const float bv = BIASRELU ? bias[n] : 0.0f;
#pragma unroll
        for (int f = 0; f < 4; ++f) {
#pragma unroll
            for (int r = 0; r < 4; ++r) {
                const int m = m0 + wm + f * 16 + rbase + r;
                float v = acc[f][g][r] + bv;
                if (BIASRELU) v = v > 0.0f ? v : 0.0f;
                if (OMODE == 0)
                    ((float*)C)[(long)b * strideC + (long)m * ldc + n] = v;
                else if (OMODE == 1)
                    ((bf16_t*)C)[(long)b * strideC + (long)m * ldc + n] = (bf16_t)v;
                else
                    ((_Float16*)C)[(long)b * strideC + (long)m * ldc + n] = (_Float16)v;
            }
        }
    }

    if (DO_STATS) {
        float lmax[4], lsum[4];
#pragma unroll
        for (int g = 0; g < 4; ++g) {
            float m = -1e30f;
#pragma unroll
            for (int f = 0; f < 4; ++f)
#pragma unroll
                for (int r = 0; r < 4; ++r) m = fmaxf(m, acc[f][g][r]);
            m = fmaxf(m, __shfl_xor(m, 16));
            m = fmaxf(m, __shfl_xor(m, 32));
            float s = 0.0f;
#pragma unroll
            for (int f = 0; f < 4; ++f)
#pragma unroll
                for (int r = 0; r < 4; ++r) s += __expf(acc[f][g][r] - m);
            s += __shfl_xor(s, 16);
            s += __shfl_xor(s, 32);
            lmax[g] = m; lsum[g] = s;
        }
        if (lane < 16) {
#pragma unroll
            for (int g = 0; g < 4; ++g) {
                smx[wid][g][lane] = lmax[g];
                ssm[wid][g][lane] = lsum[g];
            }
        }
        __syncthreads();
        if (tid < 128) {
            const int pair = tid >> 6;
            const int idx  = tid & 63;
            const int g = idx >> 4, f2 = idx & 15;
            const float m0v = smx[pair][g][f2], m1v = smx[pair + 2][g][f2];
            const float M = fmaxf(m0v, m1v);
            const float L = ssm[pair][g][f2] * __expf(m0v - M) +
                            ssm[pair + 2][g][f2] * __expf(m1v - M);
            const int n = n0 + pair * 64 + g * 16 + f2;
            const long o = ((long)b * 16 + blockIdx.y) * NN + n;
            pm[o] = M;
            pl[o] = L;
        }
    }
}

// ---------------------------------------------------------------------------
// Merge 16 per-m-tile partials per column into c2[n] = (mx + ln L) * log2(e).
// Then P~[m,n] = exp2(St[m,n]*log2e - c2[n]).
// ---------------------------------------------------------------------------
__global__ __launch_bounds__(256)
void stats_combine(const float* __restrict__ pm, const float* __restrict__ pl,
                   float* __restrict__ c2)
{
    const int i = blockIdx.x * 256 + threadIdx.x;
    const int b = i >> 11, n = i & 2047;
    float M = -1e30f, L = 0.0f;
#pragma unroll
    for (int t = 0; t < 16; ++t) {
        const long o = ((long)b * 16 + t) * NN + n;
        const float m = pm[o], l = pl[o];
        const float nm = fmaxf(M, m);
        L = L * __expf(M - nm) + l * __expf(m - nm);
        M = nm;
    }
    c2[i] = (M + logf(L)) * LOG2E;
}

// ---------------------------------------------------------------------------
// out[m][u] = relu( sum_n exp2(St[m][n]*log2e - c2[n]) * qmT[u][n] + bm[u] )
// 32m x 128u block tile, K(n)-step 64, grid (64,2,BB)=1024 blocks, 4/CU.
// Bank-conflict-free LDS:
//   As padded to 68 elem/row (136 B -> 2-bank offset/row, <=2-way = free).
//   Bs XOR chunk swizzle: LDS(row,chunk) = global chunk (chunk ^ (row&7));
//   staging permutes the global source (free), reads apply the same XOR.
// ---------------------------------------------------------------------------
#define APAD 68
__global__ __launch_bounds__(256, 4)
void att_out(const _Float16* __restrict__ St, const bf16_t* __restrict__ qmT,
             const float* __restrict__ c2, const float* __restrict__ bm,
             float* __restrict__ out)
{
    const int b  = blockIdx.z;
    const int m0 = blockIdx.x * 32;
    const int u0 = blockIdx.y * 128;
    const _Float16* S  = St  + (long)b * NN * NN;
    const bf16_t*   Q  = qmT + (long)b * 256 * NN;
    const float*    C2 = c2  + b * NN;
    float*          O  = out + (long)b * NN * 256;

    __shared__ bf16_t As[32 * APAD];  // 4.25 KB  P-tile (exp'd, bf16, padded)
    __shared__ bf16_t Bs[128 * 64];   // 16 KB    qmT tile (XOR-swizzled)

    const int tid  = threadIdx.x;
    const int wid  = tid >> 6, lane = tid & 63;
    const int wm2  = (wid >> 1) * 16;      // m-half per wave (0 or 16)
    const int wu   = (wid & 1) * 64;       // u-half per wave (0 or 64)
    const int fr   = lane & 15;
    const int u16  = lane >> 4;            // 0..3
    const int kb   = u16 * 8;
    const int fsw  = fr & 7;               // read-side XOR for Bs
    const int arow = tid >> 3;             // 0..31  (A staging row)
    const int aseg = tid & 7;              // 8 halves each

    const _Float16* Srow = S + (long)(m0 + arow) * NN + aseg * 8;

    floatx4 acc[4] = {};   // [g: u frags]

    for (int n0 = 0; n0 < NN; n0 += 64) {
        // B: qmT 128 rows x 64 cols bf16, 4 rounds of 256x16B, source-swizzled
#pragma unroll
        for (int r = 0; r < 4; ++r) {
            const int lin = tid + r * 256;
            const int rw  = lin >> 3, kc = lin & 7;
            const int kcs = kc ^ (rw & 7);
            gl_lds16(Q + (long)(u0 + rw) * NN + n0 + kcs * 8, Bs + lin * 8);
        }
        // A: St 32x64 fp16, exp2(s*log2e - c2), pack bf16 -> padded LDS
        const halfx8 hv = *(const halfx8*)(Srow + n0);
        const float4 ca = *(const float4*)(C2 + n0 + aseg * 8);
        const float4 cb = *(const float4*)(C2 + n0 + aseg * 8 + 4);
        bf16x8 p;
        p[0] = (bf16_t)exp2f(fmaf((float)hv[0], LOG2E, -ca.x));
        p[1] = (bf16_t)exp2f(fmaf((float)hv[1], LOG2E, -ca.y));
        p[2] = (bf16_t)exp2f(fmaf((float)hv[2], LOG2E, -ca.z));
        p[3] = (bf16_t)exp2f(fmaf((float)hv[3], LOG2E, -ca.w));
        p[4] = (bf16_t)exp2f(fmaf((float)hv[4], LOG2E, -cb.x));
        p[5] = (bf16_t)exp2f(fmaf((float)hv[5], LOG2E, -cb.y));
        p[6] = (bf16_t)exp2f(fmaf((float)hv[6], LOG2E, -cb.z));
        p[7] = (bf16_t)exp2f(fmaf((float)hv[7], LOG2E, -cb.w));
        *(bf16x8*)(As + arow * APAD + aseg * 8) = p;
        __syncthreads();

        bf16x8 af[2], bg[4][2];
#pragma unroll
        for (int j = 0; j < 2; ++j)
            af[j] = *(const bf16x8*)(As + (wm2 + fr) * APAD + j * 32 + kb);
#pragma unroll
        for (int g = 0; g < 4; ++g)
#pragma unroll
            for (int j = 0; j < 2; ++j) {
                const int chunk = (j * 4 + u16) ^ fsw;
                bg[g][j] = *(const bf16x8*)(Bs + (wu + g * 16 + fr) * 64 + chunk * 8);
            }
#pragma unroll
        for (int j = 0; j < 2; ++j)
#pragma unroll
            for (int g = 0; g < 4; ++g)
                acc[g] = __builtin_amdgcn_mfma_f32_16x16x32_bf16(af[j], bg[g][j], acc[g], 0, 0, 0);
        __syncthreads();
    }

    // D layout: col(u) = lane&15, row(m) = (lane>>4)*4 + reg
    const int rbase = u16 * 4;
#pragma unroll
    for (int g = 0; g < 4; ++g) {
        const int u = u0 + wu + g * 16 + fr;
        const float bvv = bm[u];
#pragma unroll
        for (int r = 0; r < 4; ++r) {
            const int m = m0 + wm2 + rbase + r;
            const float v = acc[g][r] + bvv;
            O[(long)m * 256 + u] = v > 0.0f ? v : 0.0f;
        }
    }
}

// ---------------------------------------------------------------------------
// Helpers
// ---------------------------------------------------------------------------
__global__ __launch_bounds__(256)
void cvt_bf16(const float* __restrict__ x, bf16_t* __restrict__ y)
{
    const long i = ((long)blockIdx.x * 256 + threadIdx.x) * 8;
    const float4 a = *(const float4*)(x + i);
    const float4 b = *(const float4*)(x + i + 4);
    bf16x8 o;
    o[0] = (bf16_t)a.x; o[1] = (bf16_t)a.y; o[2] = (bf16_t)a.z; o[3] = (bf16_t)a.w;
    o[4] = (bf16_t)b.x; o[5] = (bf16_t)b.y; o[6] = (bf16_t)b.z; o[7] = (bf16_t)b.w;
    *(bf16x8*)(y + i) = o;
}

// z=0: Wq -> WqkT[0:256), z=1: Wk -> WqkT[256:512), z=2: Wm -> WmT.
// Block (0,0,0) also concatenates [bq|bk] into bqk.
__global__ __launch_bounds__(256)
void prep_w(const float* __restrict__ Wq, const float* __restrict__ Wk,
            const float* __restrict__ Wm, const float* __restrict__ bq,
            const float* __restrict__ bk, bf16_t* __restrict__ WqkT,
            bf16_t* __restrict__ WmT, float* __restrict__ bqk)
{
    const int z = blockIdx.z;
    const float* W = (z == 0) ? Wq : (z == 1) ? Wk : Wm;
    bf16_t* Wt = (z == 0) ? WqkT : (z == 1) ? (WqkT + 256 * 256) : WmT;
    __shared__ float t[32][33];
    const int n0 = blockIdx.x * 32, k0 = blockIdx.y * 32;
    const int tx = threadIdx.x & 31, ty = threadIdx.x >> 5;
    for (int i = ty; i < 32; i += 8) t[i][tx] = W[(k0 + i) * 256 + n0 + tx];
    __syncthreads();
    for (int i = ty; i < 32; i += 8) Wt[(n0 + i) * 256 + k0 + tx] = (bf16_t)t[tx][i];
    if (z == 0 && blockIdx.x == 0 && blockIdx.y == 0) {
        bqk[threadIdx.x]       = bq[threadIdx.x];
        bqk[256 + threadIdx.x] = bk[threadIdx.x];
    }
}

extern "C" void kernel_launch(void* const* d_in, const int* in_sizes, int n_in,
                              void* d_out, int out_size, void* d_ws, size_t ws_size,
                              hipStream_t stream)
{
    (void)in_sizes; (void)n_in; (void)out_size; (void)ws_size;
    const float* x  = (const float*)d_in[0];
    const float* Wq = (const float*)d_in[1];
    const float* bq = (const float*)d_in[2];
    const float* Wk = (const float*)d_in[3];
    const float* bk = (const float*)d_in[4];
    const float* Wm = (const float*)d_in[5];
    const float* bm = (const float*)d_in[6];
    float* out = (float*)d_out;

    // Workspace: St fp16 67.1 MB | x_bf 8.4 | qk 16.8 | qmT 8.4 |
    // WqkT 0.26 | WmT 0.13 | bqk | pm/pl 2x1 MB | c2 64 KB  (~103 MB)
    char* w = (char*)d_ws;
    _Float16* St   = (_Float16*)w;                  w += (size_t)BB * NN * NN * 2;
    bf16_t* x_bf   = (bf16_t*)w;                    w += (size_t)MTOT * 256 * 2;
    bf16_t* qk     = (bf16_t*)w;                    w += (size_t)MTOT * 512 * 2;
    bf16_t* qmT    = (bf16_t*)w;                    w += (size_t)MTOT * 256 * 2;
    bf16_t* WqkT   = (bf16_t*)w;                    w += 512 * 256 * 2;
    bf16_t* WmT    = (bf16_t*)w;                    w += 256 * 256 * 2;
    float*  bqk    = (float*)w;                     w += 512 * 4;
    float*  pm     = (float*)w;                     w += (size_t)BB * 16 * NN * 4;
    float*  pl     = (float*)w;                     w += (size_t)BB * 16 * NN * 4;
    float*  c2b    = (float*)w;

    cvt_bf16<<<dim3(MTOT * 256 / (256 * 8)), 256, 0, stream>>>(x, x_bf);
    prep_w<<<dim3(8, 8, 3), 256, 0, stream>>>(Wq, Wk, Wm, bq, bk, WqkT, WmT, bqk);

    // [q | k] = relu(x @ [Wq|Wk] + [bq|bk])  (bf16, ldc=512)
    gemm_nt<1, true, false><<<dim3(4, 128, 1), 256, 0, stream>>>(
        x_bf, WqkT, qk, bqk, 256, 256, 512, 0, 0, 0, nullptr, nullptr);

    // qmT[u][m] = sum_k WmT[u][k] * q[m][k]  (= (q @ Wm)^T, bf16, ldc=NN)
    gemm_nt<1, false, false><<<dim3(16, 2, BB), 256, 0, stream>>>(
        WmT, qk, qmT, nullptr, 256, 512, NN,
        0, (long)NN * 512, (long)256 * NN, nullptr, nullptr);

    // St[m][n] = q[m]·k[n]  (fp16 out) + fused per-column softmax stats
    gemm_nt<2, false, true><<<dim3(16, 16, BB), 256, 0, stream>>>(
        qk, qk + 256, St, nullptr, 512, 512, NN,
        (long)NN * 512, (long)NN * 512, (long)NN * NN, pm, pl);

    stats_combine<<<dim3(MTOT / 256), 256, 0, stream>>>(pm, pl, c2b);

    // out = relu(P~ @ qm + bm)   (P never materialized)
    att_out<<<dim3(64, 2, BB), 256, 0, stream>>>(St, qmT, c2b, bm, out);
}